// Round 1
// baseline (222.529 us; speedup 1.0000x reference)
//
#include <hip/hip_runtime.h>

typedef __bf16 bf16;
typedef __bf16 bf16x8 __attribute__((ext_vector_type(8)));
typedef float f32x4 __attribute__((ext_vector_type(4)));

#define MFMA16(a, b, c) __builtin_amdgcn_mfma_f32_16x16x32_bf16((a), (b), (c), 0, 0, 0)

static __device__ __forceinline__ bf16x8 ldg8(const bf16* p) {
  return *(const bf16x8*)p;
}
static __device__ __forceinline__ unsigned cvt_pk_bf16(float lo, float hi) {
  unsigned d;
  asm("v_cvt_pk_bf16_f32 %0, %1, %2" : "=v"(d) : "v"(lo), "v"(hi));
  return d;
}
// vdst[32:63] <-> vsrc[0:31]
static __device__ __forceinline__ void pl32_swap(unsigned& a, unsigned& b) {
  asm("v_permlane32_swap_b32 %0, %1" : "+v"(a), "+v"(b));
}
// vdst rows 1,3 (16-lane) <-> vsrc rows 0,2
static __device__ __forceinline__ void pl16_swap(unsigned& a, unsigned& b) {
  asm("v_permlane16_swap_b32 %0, %1" : "+v"(a), "+v"(b));
}

// ===========================================================================
// Established: 5 fp32 inputs, FP32 output, ws >= 61.4MB (r14). Ladder:
// 803 -> 675 -> 365 (coalesced+swizzle) -> 258 (packed GEMMs) -> 246 -> 244
// -> 221 (32 Q rows/wave). Counters at 221: flash 108us, MfmaUtil 27,
// VALUBusy 41, LDS port ~45%, bank-conflict 2.1M -> latency-bound, not
// roofline. This round: in-register P via SWAPPED QK^T (mfma(K,Q) puts
// q=l16 = PV A-frag row) + cvt_pk_bf16 + permlane{32,16}_swap quad
// redistribution -- removes the P LDS round trip (36 LDS ops/wave-tile,
// 18KB LDS, the bank-conflict source, and the write->wait->read bubble
// between the MFMA groups). Freed LDS funds K/V double-buffer: ONE barrier
// per tile. s_setprio around MFMA clusters (T5).
// ===========================================================================

__global__ __launch_bounds__(256) void cvt_pack_x(const float* __restrict__ x,
                                                  bf16* __restrict__ Xp) {
  int mt = blockIdx.x, kc = blockIdx.y;
  int row = threadIdx.x >> 4;
  int c4 = (threadIdx.x & 15) * 4;
  bf16* tile = Xp + ((size_t)mt * 8 + kc) * 4096;
#pragma unroll
  for (int i = 0; i < 4; i++) {
    int r = i * 16 + row;
    const float* src = x + (size_t)(mt * 64 + r) * 512 + kc * 64 + c4;
    float4 v = *(const float4*)src;
    bf16* d = tile + r * 64 + c4;
    d[0] = (bf16)v.x; d[1] = (bf16)v.y; d[2] = (bf16)v.z; d[3] = (bf16)v.w;
  }
}

__global__ __launch_bounds__(256) void transpose_pack_w(const float* __restrict__ W,
                                                        bf16* __restrict__ Wp,
                                                        int N, int KC) {
  __shared__ bf16 tile[64][65];
  int kc = blockIdx.x, nt = blockIdx.y;
  int c = threadIdx.x & 63;
  int r4 = threadIdx.x >> 6;
#pragma unroll
  for (int i = 0; i < 16; i++) {
    int r = r4 * 16 + i;
    tile[r][c] = (bf16)W[(size_t)(kc * 64 + r) * N + nt * 64 + c];
  }
  __syncthreads();
  bf16* dst = Wp + ((size_t)nt * KC + kc) * 4096;
#pragma unroll
  for (int i = 0; i < 16; i++) {
    int r = r4 * 16 + i;
    dst[r * 64 + c] = tile[c][r];
  }
}

// ---------------------------------------------------------------------------
// Packed-tile GEMM core (r16-proven).
// ---------------------------------------------------------------------------
__device__ __forceinline__ void gemm_core_packed(const bf16* __restrict__ Ap,
                                                 const bf16* __restrict__ Bp,
                                                 int KC, bf16* Atile, bf16* Btile,
                                                 int tid, int wave, int l16,
                                                 int quad, f32x4 acc[4]) {
  for (int kc = 0; kc < KC; kc++) {
    __syncthreads();
    const bf16* ag = Ap + (size_t)kc * 4096;
    const bf16* bg = Bp + (size_t)kc * 4096;
#pragma unroll
    for (int rnd = 0; rnd < 2; rnd++) {
      int e = (rnd * 256 + tid) * 8;
      int row = e >> 6;
      int c16 = (e & 63) >> 3;
      int unit = row * 8 + (c16 ^ (row & 7));
      *(bf16x8*)&Atile[unit * 8] = ldg8(ag + e);
      *(bf16x8*)&Btile[unit * 8] = ldg8(bg + e);
    }
    __syncthreads();

    int ar = wave * 16 + l16;
    bf16x8 a0 = *(const bf16x8*)&Atile[(ar * 8 + (quad ^ (ar & 7))) * 8];
    bf16x8 a1 = *(const bf16x8*)&Atile[(ar * 8 + ((4 + quad) ^ (ar & 7))) * 8];
#pragma unroll
    for (int ct = 0; ct < 4; ct++) {
      int n = ct * 16 + l16;
      bf16x8 b0 = *(const bf16x8*)&Btile[(n * 8 + (quad ^ (n & 7))) * 8];
      bf16x8 b1 = *(const bf16x8*)&Btile[(n * 8 + ((4 + quad) ^ (n & 7))) * 8];
      acc[ct] = MFMA16(a0, b0, acc[ct]);
      acc[ct] = MFMA16(a1, b1, acc[ct]);
    }
  }
}

// ---------------------------------------------------------------------------
// QKV projection. Q pre-scaled by 0.125 (exact pow2). Q,K:[bh][n][d]; V tiled
// [bh][n>>6][d][n&63].
// ---------------------------------------------------------------------------
__global__ __launch_bounds__(256) void qkv_gemm(const bf16* __restrict__ Xp,
                                                const bf16* __restrict__ Wp1,
                                                const float* __restrict__ bqkv,
                                                bf16* __restrict__ Q,
                                                bf16* __restrict__ Kh,
                                                bf16* __restrict__ Vt) {
  int mt = blockIdx.x, nt = blockIdx.y;
  int tid = threadIdx.x;
  int wave = tid >> 6, lane = tid & 63;
  int l16 = lane & 15, quad = lane >> 4;

  __shared__ __align__(16) bf16 Atile[4096];
  __shared__ __align__(16) bf16 Btile[4096];

  f32x4 acc[4] = {};
  gemm_core_packed(Xp + (size_t)mt * 8 * 4096, Wp1 + (size_t)nt * 8 * 4096, 8,
                   Atile, Btile, tid, wave, l16, quad, acc);

#pragma unroll
  for (int ct = 0; ct < 4; ct++) {
    int c = nt * 64 + ct * 16 + l16;
    float bias = bqkv[c];
    int which = c >> 9, inner = c & 511;
    int h = inner >> 6, d = inner & 63;
#pragma unroll
    for (int r = 0; r < 4; r++) {
      int m = mt * 64 + wave * 16 + quad * 4 + r;
      int b = m >> 12, n = m & 4095;
      int bh = b * 8 + h;
      float v = acc[ct][r] + bias;
      if (which == 0)
        Q[((size_t)bh * 4096 + n) * 64 + d] = (bf16)(v * 0.125f);
      else if (which == 1)
        Kh[((size_t)bh * 4096 + n) * 64 + d] = (bf16)v;
      else
        Vt[(((size_t)bh * 64 + (n >> 6)) * 64 + d) * 64 + (n & 63)] = (bf16)v;
    }
  }
}

// ---------------------------------------------------------------------------
// flash_partial v17: grid (32 strip128, 16 bh, 2 half), block 256 = 4 waves,
// 32 Q rows/wave. Swapped QK^T: s = mfma(K_frag, Q_frag) -> S^T with
// q = l16 (the PV A-frag row), kv = ct*16 + quad*4 + r. exp in reg, pack
// with v_cvt_pk_bf16_f32, redistribute kv across quads with
// permlane32_swap + permlane16_swap: (D0,D2)=pl16(pl32(u0,u1)),
// (D1,D3)=pl16(pl32(v0,v1)) -> PV A-frag directly. No P in LDS.
// K/V double-buffered (2x16KB), ONE barrier/tile; reg-prefetch issued
// after the barrier so nothing is vmcnt-outstanding at barriers.
// ---------------------------------------------------------------------------
__global__ __launch_bounds__(256, 4) void flash_partial(const bf16* __restrict__ Q,
                                                        const bf16* __restrict__ K,
                                                        const bf16* __restrict__ Vt,
                                                        bf16* __restrict__ Opart,
                                                        float* __restrict__ Lpart) {
  int strip = blockIdx.x, bh = blockIdx.y, half = blockIdx.z;
  int tid = threadIdx.x;
  int wave = tid >> 6, lane = tid & 63;
  int l16 = lane & 15, quad = lane >> 4;

  const bf16* Qh = Q + (size_t)bh * 4096 * 64;
  const bf16* Kg = K + ((size_t)bh * 4096 + half * 2048) * 64;
  const bf16* Vg = Vt + (size_t)bh * 64 * 4096 + (size_t)half * 2048 * 64;

  __shared__ __align__(16) bf16 Klds[2][4096];
  __shared__ __align__(16) bf16 Vlds[2][4096];

  int qbase = strip * 128 + wave * 32;
  bf16x8 aq[2][2];  // B-frags now (col = q = l16), same layout as before
#pragma unroll
  for (int mt = 0; mt < 2; mt++) {
    const bf16* qr = Qh + (size_t)(qbase + mt * 16 + l16) * 64;
    aq[mt][0] = ldg8(qr + quad * 8);
    aq[mt][1] = ldg8(qr + 32 + quad * 8);
  }

  f32x4 o[2][4] = {};
  float l_lane[2] = {0.f, 0.f};

  int e0 = tid * 8, e1 = (256 + tid) * 8;
  int r0 = e0 >> 6, r1 = e1 >> 6;
  int u0 = r0 * 8 + (((e0 & 63) >> 3) ^ (r0 & 7));
  int u1 = r1 * 8 + (((e1 & 63) >> 3) ^ (r1 & 7));

  bf16x8 kp0 = ldg8(Kg + e0), kp1 = ldg8(Kg + e1);
  bf16x8 vp0 = ldg8(Vg + e0), vp1 = ldg8(Vg + e1);

#pragma unroll 2
  for (int t = 0; t < 32; t++) {
    int cur = t & 1;
    bf16* kl = Klds[cur];
    bf16* vl = Vlds[cur];
    // stage tile t (writes to buf[cur]; last readers of buf[cur] finished
    // before barrier(t-1), so no barrier needed before the writes)
    *(bf16x8*)&kl[u0 * 8] = kp0;
    *(bf16x8*)&kl[u1 * 8] = kp1;
    *(bf16x8*)&vl[u0 * 8] = vp0;
    *(bf16x8*)&vl[u1 * 8] = vp1;
    __syncthreads();

    if (t < 31) {  // prefetch tile t+1 (in flight across the whole compute)
      const bf16* kg = Kg + (size_t)(t + 1) * 4096;
      const bf16* vg = Vg + (size_t)(t + 1) * 4096;
      kp0 = ldg8(kg + e0);
      kp1 = ldg8(kg + e1);
      vp0 = ldg8(vg + e0);
      vp1 = ldg8(vg + e1);
    }

#pragma unroll
    for (int h2 = 0; h2 < 2; h2++) {  // two 32-kv halves of the 64-kv tile
      // ---- S^T = K Q^T (swapped operands) ----
      f32x4 s[2][2] = {};
      __builtin_amdgcn_s_setprio(1);
#pragma unroll
      for (int c2 = 0; c2 < 2; c2++) {
        int n = h2 * 32 + c2 * 16 + l16;  // kv row
        bf16x8 k0 = *(const bf16x8*)&kl[(n * 8 + (quad ^ (n & 7))) * 8];
        bf16x8 k1 = *(const bf16x8*)&kl[(n * 8 + ((4 + quad) ^ (n & 7))) * 8];
#pragma unroll
        for (int mt = 0; mt < 2; mt++) {
          s[mt][c2] = MFMA16(k0, aq[mt][0], s[mt][c2]);
          s[mt][c2] = MFMA16(k1, aq[mt][1], s[mt][c2]);
        }
      }
      __builtin_amdgcn_s_setprio(0);

      // ---- p = exp(s); accumulate l; pack+redistribute into PV A-frags ----
      bf16x8 pa[2];
#pragma unroll
      for (int mt = 0; mt < 2; mt++) {
        unsigned ue[2], wo[2];
#pragma unroll
        for (int c2 = 0; c2 < 2; c2++) {
          float p0 = __expf(s[mt][c2][0]);
          float p1 = __expf(s[mt][c2][1]);
          float p2 = __expf(s[mt][c2][2]);
          float p3 = __expf(s[mt][c2][3]);
          l_lane[mt] += (p0 + p1) + (p2 + p3);
          ue[c2] = cvt_pk_bf16(p0, p1);  // kv = base+0,1
          wo[c2] = cvt_pk_bf16(p2, p3);  // kv = base+2,3
        }
        // quad q' needs kv q'*8..q'*8+7 of this 32-kv half:
        pl32_swap(ue[0], ue[1]);
        pl16_swap(ue[0], ue[1]);  // ue[0]=D0 (kv q'*8+0,1), ue[1]=D2 (+4,5)
        pl32_swap(wo[0], wo[1]);
        pl16_swap(wo[0], wo[1]);  // wo[0]=D1 (+2,3),        wo[1]=D3 (+6,7)
        union { bf16x8 v; unsigned d[4]; } pk;
        pk.d[0] = ue[0];
        pk.d[1] = wo[0];
        pk.d[2] = ue[1];
        pk.d[3] = wo[1];
        pa[mt] = pk.v;
      }

      // ---- O += P V (V-frags shared across both m-tiles) ----
      __builtin_amdgcn_s_setprio(1);
#pragma unroll
      for (int ct = 0; ct < 4; ct++) {
        int d = ct * 16 + l16;
        bf16x8 bv = *(const bf16x8*)&vl[(d * 8 + ((h2 * 4 + quad) ^ (d & 7))) * 8];
        o[0][ct] = MFMA16(pa[0], bv, o[0][ct]);
        o[1][ct] = MFMA16(pa[1], bv, o[1][ct]);
      }
      __builtin_amdgcn_s_setprio(0);
    }
  }

  // ---- epilogue: partial o (bf16) + l (fp32) ----
  float lf[2];
#pragma unroll
  for (int mt = 0; mt < 2; mt++) {
    float l = l_lane[mt];  // per-lane partial for q = mt*16 + l16
    l += __shfl_xor(l, 16);
    l += __shfl_xor(l, 32);
    lf[mt] = l;
  }
  size_t ub = ((size_t)half * 16 + bh) * 32 + strip;
  bf16* op = Opart + ub * 8192;
#pragma unroll
  for (int mt = 0; mt < 2; mt++) {
#pragma unroll
    for (int ct = 0; ct < 4; ct++)
#pragma unroll
      for (int r = 0; r < 4; r++)
        op[(wave * 32 + mt * 16 + quad * 4 + r) * 64 + ct * 16 + l16] =
            (bf16)o[mt][ct][r];
    if (quad == 0)
      Lpart[ub * 128 + wave * 32 + mt * 16 + l16] = lf[mt];
  }
}

// ---------------------------------------------------------------------------
// flash_combine: Ap(packed) = (o0+o1)/(l0+l1). Grid (64 qt64, 16 bh).
// ---------------------------------------------------------------------------
__global__ __launch_bounds__(256) void flash_combine(const bf16* __restrict__ Opart,
                                                     const float* __restrict__ Lpart,
                                                     bf16* __restrict__ Ap) {
  int qt = blockIdx.x, bh = blockIdx.y;
  int col = threadIdx.x & 63;
  int rg = threadIdx.x >> 6;
  int strip = qt >> 1;
  int rbase = (qt & 1) * 64;
  size_t u0 = (size_t)bh * 32 + strip;
  size_t u1 = ((size_t)16 + bh) * 32 + strip;
  int b = bh >> 3, h = bh & 7;
  bf16* apt = Ap + (((size_t)(b * 64 + qt)) * 8 + h) * 4096;
#pragma unroll
  for (int i = 0; i < 16; i++) {
    int r64 = rg * 16 + i;
    int row = rbase + r64;
    float o0 = (float)Opart[u0 * 8192 + row * 64 + col];
    float o1 = (float)Opart[u1 * 8192 + row * 64 + col];
    float ls = Lpart[u0 * 128 + row] + Lpart[u1 * 128 + row];
    apt[r64 * 64 + col] = (bf16)((o0 + o1) / ls);
  }
}

// ---------------------------------------------------------------------------
// Output projection: Ap(packed) @ Wp2 -> FP32 out.
// ---------------------------------------------------------------------------
__global__ __launch_bounds__(256) void out_gemm(const bf16* __restrict__ Ap,
                                                const bf16* __restrict__ Wp2,
                                                const float* __restrict__ bout,
                                                float* __restrict__ Out) {
  int mt = blockIdx.x, nt = blockIdx.y;
  int tid = threadIdx.x;
  int wave = tid >> 6, lane = tid & 63;
  int l16 = lane & 15, quad = lane >> 4;

  __shared__ __align__(16) bf16 Atile[4096];
  __shared__ __align__(16) bf16 Btile[4096];

  f32x4 acc[4] = {};
  gemm_core_packed(Ap + (size_t)mt * 8 * 4096, Wp2 + (size_t)nt * 8 * 4096, 8,
                   Atile, Btile, tid, wave, l16, quad, acc);

#pragma unroll
  for (int ct = 0; ct < 4; ct++) {
    int c = nt * 64 + ct * 16 + l16;
    float bias = bout[c];
#pragma unroll
    for (int r = 0; r < 4; r++) {
      int m = mt * 64 + wave * 16 + quad * 4 + r;
      Out[(size_t)m * 512 + c] = acc[ct][r] + bias;
    }
  }
}

// ---------------------------------------------------------------------------
// ws: Q 0 | K 8388608 | Vt 16777216 | Ap 25165824 | Wp1 33554432 |
//     Wp2 35127296 | Xp 35651584 | Opart 44040192 | Lpart 60817408 (.52MB)
// ---------------------------------------------------------------------------
extern "C" void kernel_launch(void* const* d_in, const int* in_sizes, int n_in,
                              void* d_out, int out_size, void* d_ws,
                              size_t ws_size, hipStream_t stream) {
  const float* x = (const float*)d_in[0];
  const float* w_qkv = (const float*)d_in[1];
  const float* b_qkv = (const float*)d_in[2];
  const float* w_out = (const float*)d_in[3];
  const float* b_out = (const float*)d_in[4];
  float* out = (float*)d_out;

  char* ws = (char*)d_ws;
  bf16* Q = (bf16*)(ws + 0);
  bf16* K = (bf16*)(ws + 8388608);
  bf16* Vt = (bf16*)(ws + 16777216);
  bf16* Ap = (bf16*)(ws + 25165824);
  bf16* Wp1 = (bf16*)(ws + 33554432);
  bf16* Wp2 = (bf16*)(ws + 35127296);
  bf16* Xp = (bf16*)(ws + 35651584);
  bf16* Opart = (bf16*)(ws + 44040192);
  float* Lpart = (float*)(ws + 60817408);

  cvt_pack_x<<<dim3(128, 8), 256, 0, stream>>>(x, Xp);
  transpose_pack_w<<<dim3(8, 24), 256, 0, stream>>>(w_qkv, Wp1, 1536, 8);
  transpose_pack_w<<<dim3(8, 8), 256, 0, stream>>>(w_out, Wp2, 512, 8);
  qkv_gemm<<<dim3(128, 24), 256, 0, stream>>>(Xp, Wp1, b_qkv, Q, K, Vt);
  flash_partial<<<dim3(32, 16, 2), 256, 0, stream>>>(Q, K, Vt, Opart, Lpart);
  flash_combine<<<dim3(64, 16), 256, 0, stream>>>(Opart, Lpart, Ap);
  out_gemm<<<dim3(128, 8), 256, 0, stream>>>(Ap, Wp2, b_out, out);
}

// Round 2
// 204.463 us; speedup vs baseline: 1.0884x; 1.0884x over previous
//
#include <hip/hip_runtime.h>

typedef __bf16 bf16;
typedef __bf16 bf16x8 __attribute__((ext_vector_type(8)));
typedef float f32x4 __attribute__((ext_vector_type(4)));
typedef unsigned u32x4 __attribute__((ext_vector_type(4)));

#define MFMA16(a, b, c) __builtin_amdgcn_mfma_f32_16x16x32_bf16((a), (b), (c), 0, 0, 0)

static __device__ __forceinline__ bf16x8 ldg8(const bf16* p) {
  return *(const bf16x8*)p;
}
static __device__ __forceinline__ unsigned cvt_pk_bf16(float lo, float hi) {
  unsigned d;
  asm("v_cvt_pk_bf16_f32 %0, %1, %2" : "=v"(d) : "v"(lo), "v"(hi));
  return d;
}
// vdst[32:63] <-> vsrc[0:31]
static __device__ __forceinline__ void pl32_swap(unsigned& a, unsigned& b) {
  asm("v_permlane32_swap_b32 %0, %1" : "+v"(a), "+v"(b));
}
// vdst rows 1,3 (16-lane) <-> vsrc rows 0,2
static __device__ __forceinline__ void pl16_swap(unsigned& a, unsigned& b) {
  asm("v_permlane16_swap_b32 %0, %1" : "+v"(a), "+v"(b));
}

// ===========================================================================
// Ladder: 803 -> ... -> 244 -> 221 (32 Q rows/wave) -> 222 (in-reg P via
// swapped QK + permlane; conflicts 2.1M->0 but dur FLAT -> conflicts were 3%
// of cycles, red herring). Counters now: VALU 43.9 (=~870 cyc/wave-tile,
// half of it softmax), Mfma 27.5, LDS ~8%, HBM 21%, ~30% stall;
// WRITE_SIZE 84MB vs 17MB real output -> union type-pun scratch suspect.
// This round: (1) exp2 with log2e folded into Q scale (-32 vmul/tile);
// (2) l-rowsum via ones-MFMA on the idle matrix pipe (-32 adds/tile,
// shuffle-free Lpart epilogue); (3) bit_cast not union (scratch);
// (4) KV-split x4 (2048 blocks, 16 tiles) -> up to 5 blocks/CU resident
// (LDS 32KB caps at 5; launch_bounds(256,4) only floors the allocator).
// ws re-layout (lifetime-overlapped, ends 60.3MB < 61.4MB):
//   Q 0 | K 8388608 | Vt 16777216 | Wp2 25165824 | Opart 25690112 (33.5MB)
//   | Lpart 59244544 (1MB) | Xp 25690112* | Wp1 34078720* | Ap 0*
//   (* Xp/Wp1 dead before flash overwrite by Opart; Ap overlays dead Q)
// ===========================================================================

__global__ __launch_bounds__(256) void cvt_pack_x(const float* __restrict__ x,
                                                  bf16* __restrict__ Xp) {
  int mt = blockIdx.x, kc = blockIdx.y;
  int row = threadIdx.x >> 4;
  int c4 = (threadIdx.x & 15) * 4;
  bf16* tile = Xp + ((size_t)mt * 8 + kc) * 4096;
#pragma unroll
  for (int i = 0; i < 4; i++) {
    int r = i * 16 + row;
    const float* src = x + (size_t)(mt * 64 + r) * 512 + kc * 64 + c4;
    float4 v = *(const float4*)src;
    bf16* d = tile + r * 64 + c4;
    d[0] = (bf16)v.x; d[1] = (bf16)v.y; d[2] = (bf16)v.z; d[3] = (bf16)v.w;
  }
}

__global__ __launch_bounds__(256) void transpose_pack_w(const float* __restrict__ W,
                                                        bf16* __restrict__ Wp,
                                                        int N, int KC) {
  __shared__ bf16 tile[64][65];
  int kc = blockIdx.x, nt = blockIdx.y;
  int c = threadIdx.x & 63;
  int r4 = threadIdx.x >> 6;
#pragma unroll
  for (int i = 0; i < 16; i++) {
    int r = r4 * 16 + i;
    tile[r][c] = (bf16)W[(size_t)(kc * 64 + r) * N + nt * 64 + c];
  }
  __syncthreads();
  bf16* dst = Wp + ((size_t)nt * KC + kc) * 4096;
#pragma unroll
  for (int i = 0; i < 16; i++) {
    int r = r4 * 16 + i;
    dst[r * 64 + c] = tile[c][r];
  }
}

// ---------------------------------------------------------------------------
// Packed-tile GEMM core (r16-proven).
// ---------------------------------------------------------------------------
__device__ __forceinline__ void gemm_core_packed(const bf16* __restrict__ Ap,
                                                 const bf16* __restrict__ Bp,
                                                 int KC, bf16* Atile, bf16* Btile,
                                                 int tid, int wave, int l16,
                                                 int quad, f32x4 acc[4]) {
  for (int kc = 0; kc < KC; kc++) {
    __syncthreads();
    const bf16* ag = Ap + (size_t)kc * 4096;
    const bf16* bg = Bp + (size_t)kc * 4096;
#pragma unroll
    for (int rnd = 0; rnd < 2; rnd++) {
      int e = (rnd * 256 + tid) * 8;
      int row = e >> 6;
      int c16 = (e & 63) >> 3;
      int unit = row * 8 + (c16 ^ (row & 7));
      *(bf16x8*)&Atile[unit * 8] = ldg8(ag + e);
      *(bf16x8*)&Btile[unit * 8] = ldg8(bg + e);
    }
    __syncthreads();

    int ar = wave * 16 + l16;
    bf16x8 a0 = *(const bf16x8*)&Atile[(ar * 8 + (quad ^ (ar & 7))) * 8];
    bf16x8 a1 = *(const bf16x8*)&Atile[(ar * 8 + ((4 + quad) ^ (ar & 7))) * 8];
#pragma unroll
    for (int ct = 0; ct < 4; ct++) {
      int n = ct * 16 + l16;
      bf16x8 b0 = *(const bf16x8*)&Btile[(n * 8 + (quad ^ (n & 7))) * 8];
      bf16x8 b1 = *(const bf16x8*)&Btile[(n * 8 + ((4 + quad) ^ (n & 7))) * 8];
      acc[ct] = MFMA16(a0, b0, acc[ct]);
      acc[ct] = MFMA16(a1, b1, acc[ct]);
    }
  }
}

// ---------------------------------------------------------------------------
// QKV projection. Q pre-scaled by 0.125*log2(e) so softmax uses exp2.
// Q,K:[bh][n][d]; V tiled [bh][n>>6][d][n&63].
// ---------------------------------------------------------------------------
__global__ __launch_bounds__(256) void qkv_gemm(const bf16* __restrict__ Xp,
                                                const bf16* __restrict__ Wp1,
                                                const float* __restrict__ bqkv,
                                                bf16* __restrict__ Q,
                                                bf16* __restrict__ Kh,
                                                bf16* __restrict__ Vt) {
  int mt = blockIdx.x, nt = blockIdx.y;
  int tid = threadIdx.x;
  int wave = tid >> 6, lane = tid & 63;
  int l16 = lane & 15, quad = lane >> 4;

  __shared__ __align__(16) bf16 Atile[4096];
  __shared__ __align__(16) bf16 Btile[4096];

  f32x4 acc[4] = {};
  gemm_core_packed(Xp + (size_t)mt * 8 * 4096, Wp1 + (size_t)nt * 8 * 4096, 8,
                   Atile, Btile, tid, wave, l16, quad, acc);

#pragma unroll
  for (int ct = 0; ct < 4; ct++) {
    int c = nt * 64 + ct * 16 + l16;
    float bias = bqkv[c];
    int which = c >> 9, inner = c & 511;
    int h = inner >> 6, d = inner & 63;
#pragma unroll
    for (int r = 0; r < 4; r++) {
      int m = mt * 64 + wave * 16 + quad * 4 + r;
      int b = m >> 12, n = m & 4095;
      int bh = b * 8 + h;
      float v = acc[ct][r] + bias;
      if (which == 0)
        Q[((size_t)bh * 4096 + n) * 64 + d] = (bf16)(v * 0.18033688f);  // 0.125*log2e
      else if (which == 1)
        Kh[((size_t)bh * 4096 + n) * 64 + d] = (bf16)v;
      else
        Vt[(((size_t)bh * 64 + (n >> 6)) * 64 + d) * 64 + (n & 63)] = (bf16)v;
    }
  }
}

// ---------------------------------------------------------------------------
// flash_partial v18: grid (32 strip128, 16 bh, 4 quarter), block 256 = 4
// waves, 32 Q rows/wave, 16 KV-tiles of 64. Swapped QK^T -> in-reg P
// (cvt_pk + permlane32/16). exp2 (scale folded into Q). l-rowsum via
// ones-MFMA (acc_l C-layout row=quad*4+r -> shuffle-free Lpart store).
// K/V double-buffered, ONE barrier/tile, reg-prefetch after barrier.
// ---------------------------------------------------------------------------
__global__ __launch_bounds__(256, 4) void flash_partial(const bf16* __restrict__ Q,
                                                        const bf16* __restrict__ K,
                                                        const bf16* __restrict__ Vt,
                                                        bf16* __restrict__ Opart,
                                                        float* __restrict__ Lpart) {
  int strip = blockIdx.x, bh = blockIdx.y, qtr = blockIdx.z;
  int tid = threadIdx.x;
  int wave = tid >> 6, lane = tid & 63;
  int l16 = lane & 15, quad = lane >> 4;

  const bf16* Qh = Q + (size_t)bh * 4096 * 64;
  const bf16* Kg = K + ((size_t)bh * 4096 + qtr * 1024) * 64;
  const bf16* Vg = Vt + (size_t)bh * 64 * 4096 + (size_t)qtr * 1024 * 64;

  __shared__ __align__(16) bf16 Klds[2][4096];
  __shared__ __align__(16) bf16 Vlds[2][4096];

  int qbase = strip * 128 + wave * 32;
  bf16x8 aq[2][2];
#pragma unroll
  for (int mt = 0; mt < 2; mt++) {
    const bf16* qr = Qh + (size_t)(qbase + mt * 16 + l16) * 64;
    aq[mt][0] = ldg8(qr + quad * 8);
    aq[mt][1] = ldg8(qr + 32 + quad * 8);
  }

  bf16x8 ones;
#pragma unroll
  for (int i = 0; i < 8; i++) ones[i] = (bf16)1.0f;

  f32x4 o[2][4] = {};
  f32x4 acc_l[2] = {};

  int e0 = tid * 8, e1 = (256 + tid) * 8;
  int r0 = e0 >> 6, r1 = e1 >> 6;
  int u0 = r0 * 8 + (((e0 & 63) >> 3) ^ (r0 & 7));
  int u1 = r1 * 8 + (((e1 & 63) >> 3) ^ (r1 & 7));

  bf16x8 kp0 = ldg8(Kg + e0), kp1 = ldg8(Kg + e1);
  bf16x8 vp0 = ldg8(Vg + e0), vp1 = ldg8(Vg + e1);

#pragma unroll 2
  for (int t = 0; t < 16; t++) {
    int cur = t & 1;
    bf16* kl = Klds[cur];
    bf16* vl = Vlds[cur];
    // stage tile t (safe: last readers of buf[cur] passed barrier(t-1))
    *(bf16x8*)&kl[u0 * 8] = kp0;
    *(bf16x8*)&kl[u1 * 8] = kp1;
    *(bf16x8*)&vl[u0 * 8] = vp0;
    *(bf16x8*)&vl[u1 * 8] = vp1;
    __syncthreads();

    if (t < 15) {  // prefetch tile t+1; latency covered by compute(t)
      const bf16* kg = Kg + (size_t)(t + 1) * 4096;
      const bf16* vg = Vg + (size_t)(t + 1) * 4096;
      kp0 = ldg8(kg + e0);
      kp1 = ldg8(kg + e1);
      vp0 = ldg8(vg + e0);
      vp1 = ldg8(vg + e1);
    }

#pragma unroll
    for (int h2 = 0; h2 < 2; h2++) {  // two 32-kv halves of the 64-kv tile
      // ---- S^T = K Q^T (swapped operands) ----
      f32x4 s[2][2] = {};
      __builtin_amdgcn_s_setprio(1);
#pragma unroll
      for (int c2 = 0; c2 < 2; c2++) {
        int n = h2 * 32 + c2 * 16 + l16;  // kv row
        bf16x8 k0 = *(const bf16x8*)&kl[(n * 8 + (quad ^ (n & 7))) * 8];
        bf16x8 k1 = *(const bf16x8*)&kl[(n * 8 + ((4 + quad) ^ (n & 7))) * 8];
#pragma unroll
        for (int mt = 0; mt < 2; mt++) {
          s[mt][c2] = MFMA16(k0, aq[mt][0], s[mt][c2]);
          s[mt][c2] = MFMA16(k1, aq[mt][1], s[mt][c2]);
        }
      }
      __builtin_amdgcn_s_setprio(0);

      // ---- p = exp2(s) (log2e pre-folded); pack+redistribute to A-frags ----
      bf16x8 pa[2];
#pragma unroll
      for (int mt = 0; mt < 2; mt++) {
        unsigned ue[2], wo[2];
#pragma unroll
        for (int c2 = 0; c2 < 2; c2++) {
          float p0 = __builtin_amdgcn_exp2f(s[mt][c2][0]);
          float p1 = __builtin_amdgcn_exp2f(s[mt][c2][1]);
          float p2 = __builtin_amdgcn_exp2f(s[mt][c2][2]);
          float p3 = __builtin_amdgcn_exp2f(s[mt][c2][3]);
          ue[c2] = cvt_pk_bf16(p0, p1);  // kv = base+0,1
          wo[c2] = cvt_pk_bf16(p2, p3);  // kv = base+2,3
        }
        // quad q' needs kv q'*8..q'*8+7 of this 32-kv half:
        pl32_swap(ue[0], ue[1]);
        pl16_swap(ue[0], ue[1]);  // ue[0]=D0 (kv q'*8+0,1), ue[1]=D2 (+4,5)
        pl32_swap(wo[0], wo[1]);
        pl16_swap(wo[0], wo[1]);  // wo[0]=D1 (+2,3),        wo[1]=D3 (+6,7)
        u32x4 pk = {ue[0], wo[0], ue[1], wo[1]};
        pa[mt] = __builtin_bit_cast(bf16x8, pk);
      }

      // ---- O += P V; l += P ones (rowsum on matrix pipe) ----
      __builtin_amdgcn_s_setprio(1);
      acc_l[0] = MFMA16(pa[0], ones, acc_l[0]);
      acc_l[1] = MFMA16(pa[1], ones, acc_l[1]);
#pragma unroll
      for (int ct = 0; ct < 4; ct++) {
        int d = ct * 16 + l16;
        bf16x8 bv = *(const bf16x8*)&vl[(d * 8 + ((h2 * 4 + quad) ^ (d & 7))) * 8];
        o[0][ct] = MFMA16(pa[0], bv, o[0][ct]);
        o[1][ct] = MFMA16(pa[1], bv, o[1][ct]);
      }
      __builtin_amdgcn_s_setprio(0);
    }
  }

  // ---- epilogue: partial o (bf16) + l (fp32, shuffle-free) ----
  size_t ub = ((size_t)qtr * 16 + bh) * 32 + strip;
  bf16* op = Opart + ub * 8192;
#pragma unroll
  for (int mt = 0; mt < 2; mt++) {
#pragma unroll
    for (int ct = 0; ct < 4; ct++)
#pragma unroll
      for (int r = 0; r < 4; r++)
        op[(wave * 32 + mt * 16 + quad * 4 + r) * 64 + ct * 16 + l16] =
            (bf16)o[mt][ct][r];
    if (l16 == 0) {
#pragma unroll
      for (int r = 0; r < 4; r++)
        Lpart[ub * 128 + wave * 32 + mt * 16 + quad * 4 + r] = acc_l[mt][r];
    }
  }
}

// ---------------------------------------------------------------------------
// flash_combine: Ap(packed) = sum_q(o_q) / sum_q(l_q). Grid (64 qt64, 16 bh).
// ---------------------------------------------------------------------------
__global__ __launch_bounds__(256) void flash_combine(const bf16* __restrict__ Opart,
                                                     const float* __restrict__ Lpart,
                                                     bf16* __restrict__ Ap) {
  int qt = blockIdx.x, bh = blockIdx.y;
  int col = threadIdx.x & 63;
  int rg = threadIdx.x >> 6;
  int strip = qt >> 1;
  int rbase = (qt & 1) * 64;
  size_t u[4];
#pragma unroll
  for (int h = 0; h < 4; h++) u[h] = ((size_t)h * 16 + bh) * 32 + strip;
  int b = bh >> 3, hh = bh & 7;
  bf16* apt = Ap + (((size_t)(b * 64 + qt)) * 8 + hh) * 4096;
#pragma unroll
  for (int i = 0; i < 16; i++) {
    int r64 = rg * 16 + i;
    int row = rbase + r64;
    float os = 0.f, ls = 0.f;
#pragma unroll
    for (int h = 0; h < 4; h++) {
      os += (float)Opart[u[h] * 8192 + row * 64 + col];
      ls += Lpart[u[h] * 128 + row];
    }
    apt[r64 * 64 + col] = (bf16)(os / ls);
  }
}

// ---------------------------------------------------------------------------
// Output projection: Ap(packed) @ Wp2 -> FP32 out.
// ---------------------------------------------------------------------------
__global__ __launch_bounds__(256) void out_gemm(const bf16* __restrict__ Ap,
                                                const bf16* __restrict__ Wp2,
                                                const float* __restrict__ bout,
                                                float* __restrict__ Out) {
  int mt = blockIdx.x, nt = blockIdx.y;
  int tid = threadIdx.x;
  int wave = tid >> 6, lane = tid & 63;
  int l16 = lane & 15, quad = lane >> 4;

  __shared__ __align__(16) bf16 Atile[4096];
  __shared__ __align__(16) bf16 Btile[4096];

  f32x4 acc[4] = {};
  gemm_core_packed(Ap + (size_t)mt * 8 * 4096, Wp2 + (size_t)nt * 8 * 4096, 8,
                   Atile, Btile, tid, wave, l16, quad, acc);

#pragma unroll
  for (int ct = 0; ct < 4; ct++) {
    int c = nt * 64 + ct * 16 + l16;
    float bias = bout[c];
#pragma unroll
    for (int r = 0; r < 4; r++) {
      int m = mt * 64 + wave * 16 + quad * 4 + r;
      Out[(size_t)m * 512 + c] = acc[ct][r] + bias;
    }
  }
}

// ---------------------------------------------------------------------------
// ws layout (lifetime-overlapped; end 60,293,120 < 61.4MB):
//   Q 0 (8.39M) | K 8388608 | Vt 16777216 | Wp2 25165824 (0.52M) |
//   Opart 25690112 (33.55M) | Lpart 59244544 (1.05M)
//   Xp 25690112 (8.39M, dead after qkv) | Wp1 34078720 (1.57M, dead after
//   qkv) | Ap 0 (8.39M, overlays dead Q; written by combine)
// ---------------------------------------------------------------------------
extern "C" void kernel_launch(void* const* d_in, const int* in_sizes, int n_in,
                              void* d_out, int out_size, void* d_ws,
                              size_t ws_size, hipStream_t stream) {
  const float* x = (const float*)d_in[0];
  const float* w_qkv = (const float*)d_in[1];
  const float* b_qkv = (const float*)d_in[2];
  const float* w_out = (const float*)d_in[3];
  const float* b_out = (const float*)d_in[4];
  float* out = (float*)d_out;

  char* ws = (char*)d_ws;
  bf16* Q = (bf16*)(ws + 0);
  bf16* K = (bf16*)(ws + 8388608);
  bf16* Vt = (bf16*)(ws + 16777216);
  bf16* Wp2 = (bf16*)(ws + 25165824);
  bf16* Opart = (bf16*)(ws + 25690112);
  float* Lpart = (float*)(ws + 59244544);
  bf16* Xp = (bf16*)(ws + 25690112);   // overlays Opart region, dead pre-flash
  bf16* Wp1 = (bf16*)(ws + 34078720);  // overlays Opart region, dead pre-flash
  bf16* Ap = (bf16*)(ws + 0);          // overlays Q, dead post-flash

  cvt_pack_x<<<dim3(128, 8), 256, 0, stream>>>(x, Xp);
  transpose_pack_w<<<dim3(8, 24), 256, 0, stream>>>(w_qkv, Wp1, 1536, 8);
  transpose_pack_w<<<dim3(8, 8), 256, 0, stream>>>(w_out, Wp2, 512, 8);
  qkv_gemm<<<dim3(128, 24), 256, 0, stream>>>(Xp, Wp1, b_qkv, Q, K, Vt);
  flash_partial<<<dim3(32, 16, 4), 256, 0, stream>>>(Q, K, Vt, Opart, Lpart);
  flash_combine<<<dim3(64, 16), 256, 0, stream>>>(Opart, Lpart, Ap);
  out_gemm<<<dim3(128, 8), 256, 0, stream>>>(Ap, Wp2, b_out, out);
}